// Round 5
// baseline (679.063 us; speedup 1.0000x reference)
//
#include <hip/hip_runtime.h>
#include <hip/hip_cooperative_groups.h>
#include <math.h>

namespace cg = cooperative_groups;

#define C_CAP 1000000
#define DIM 64

#define NB 1024               // 4 blocks/CU, 16 waves/CU — cooperative co-resident
#define NWAVES (NB * 4)
#define NTILES (C_CAP / 16)   // 62500
#define NCHUNKS (C_CAP / 64)  // 15625

// ws layout (floats). The harness poisons ~1 GB of ws each iteration (seen as
// 1.024e9-byte fillBufferAligned dispatches at ~154 us in rocprof), so all
// state here is recomputed every launch; nothing persists.
#define SCORES_OFF 0          // [1,000,000] raw scores
#define P1_OFF     1000000    // [1024][2] per-block {m, l}
#define HDR_OFF    1002048    // [0] argmax (int bits)
#define PART_OFF   1002112    // [1024][64] per-block PV partials (256 KB)

// ---------------------------------------------------------------------------
// Single fused cooperative kernel.
//   Phase 1: stream keys (256 MB), write raw scores + per-block {max, sum exp}.
//            16-row (4 KB) tiles, double-buffered named-register prefetch.
//   grid.sync()
//   Phase 2: every block redundantly reduces the 1024 {m,l} pairs (8 KB, L2)
//            -> M, L_shift in registers of every thread. No extra sync needed.
//   Phase 3: selective P.V over score chunks; rows with s > M-23
//            (exp(s-M) > 1e-10, ~1e4 of 1e6) trigger coalesced 256 B value-row
//            loads. argmax captured via exact-bit equality s == M (M is the
//            fmax-chain of exactly the stored score bits -> bitwise equal).
//            Block partials stored to ws (no atomics).
//   grid.sync()
//   Phase 4: blocks 0..63 each sum one output column of the 1024 partials and
//            write out[j] = sum / L_shift; block 0 writes out[64] = argmax.
// Rationale this round: one dispatch => next rocprof top-5 either shows it
// (>=152 us, with its counters) or proves total kernel time < 152 us and the
// measured 481 us is harness poison/restore floor.
// ---------------------------------------------------------------------------
__global__ __launch_bounds__(256, 4) void nd_fused(
    const float* __restrict__ query,
    const float* __restrict__ keys,
    const float* __restrict__ values,
    float* __restrict__ ws,
    float* __restrict__ out)
{
    cg::grid_group grid = cg::this_grid();

    const int tid  = threadIdx.x;
    const int lane = tid & 63;
    const int wave = tid >> 6;
    const int cl   = lane & 15;
    const int g    = lane >> 4;
    const int wglobal = blockIdx.x * 4 + wave;

    __shared__ float s_m4[4], s_l4[4];
    __shared__ float sm[256], sl[256];
    __shared__ float sA[4][64];

    // ---------------- Phase 1: scores ----------------
    {
        const float4 q4 = ((const float4*)query)[cl];
        const float4* __restrict__ k4p = (const float4*)keys;

        float m = -1e30f, l = 0.f;
        float4 A0, A1, A2, A3;   // current tile
        float4 B0, B1, B2, B3;   // prefetch tile

#define LOADK(b0, b1, b2, b3, tt) {                                        \
        const float4* __restrict__ kp = k4p + (size_t)(tt) * 256 + lane;   \
        b0 = kp[0]; b1 = kp[64]; b2 = kp[128]; b3 = kp[192];               \
    }

#define COMPUTE(b0, b1, b2, b3, tt) {                                          \
        float s0 = fmaf(b0.x, q4.x, fmaf(b0.y, q4.y, fmaf(b0.z, q4.z, b0.w * q4.w))); \
        float s1 = fmaf(b1.x, q4.x, fmaf(b1.y, q4.y, fmaf(b1.z, q4.z, b1.w * q4.w))); \
        float s2 = fmaf(b2.x, q4.x, fmaf(b2.y, q4.y, fmaf(b2.z, q4.z, b2.w * q4.w))); \
        float s3 = fmaf(b3.x, q4.x, fmaf(b3.y, q4.y, fmaf(b3.z, q4.z, b3.w * q4.w))); \
        s0 += __shfl_xor(s0, 1); s1 += __shfl_xor(s1, 1);                      \
        s2 += __shfl_xor(s2, 1); s3 += __shfl_xor(s3, 1);                      \
        s0 += __shfl_xor(s0, 2); s1 += __shfl_xor(s1, 2);                      \
        s2 += __shfl_xor(s2, 2); s3 += __shfl_xor(s3, 2);                      \
        s0 += __shfl_xor(s0, 4); s1 += __shfl_xor(s1, 4);                      \
        s2 += __shfl_xor(s2, 4); s3 += __shfl_xor(s3, 4);                      \
        s0 += __shfl_xor(s0, 8); s1 += __shfl_xor(s1, 8);                      \
        s2 += __shfl_xor(s2, 8); s3 += __shfl_xor(s3, 8);                      \
        const float sv = (cl == 0) ? s0 : (cl == 1) ? s1 : (cl == 2) ? s2 : s3; \
        if (cl < 4) ws[SCORES_OFF + (tt) * 16 + 4 * cl + g] = sv;              \
        l += (__expf(s0) + __expf(s1)) + (__expf(s2) + __expf(s3));            \
        m = fmaxf(m, fmaxf(fmaxf(s0, s1), fmaxf(s2, s3)));                     \
    }

        int t = wglobal;             // wglobal < 4096 <= NTILES: always valid
        LOADK(A0, A1, A2, A3, t);
        while (true) {
            const int tn = t + NWAVES;
            if (tn < NTILES) LOADK(B0, B1, B2, B3, tn);
            COMPUTE(A0, A1, A2, A3, t);
            if (tn >= NTILES) break;
            t = tn + NWAVES;
            if (t < NTILES) LOADK(A0, A1, A2, A3, t);
            COMPUTE(B0, B1, B2, B3, tn);
            if (t >= NTILES) break;
        }
#undef LOADK
#undef COMPUTE

        // combine the 4 16-lane groups inside the wave
        l += __shfl_xor(l, 16); m = fmaxf(m, __shfl_xor(m, 16));
        l += __shfl_xor(l, 32); m = fmaxf(m, __shfl_xor(m, 32));

        if (lane == 0) { s_m4[wave] = m; s_l4[wave] = l; }
        __syncthreads();
        if (tid == 0) {
            float bm = s_m4[0], bl = s_l4[0];
            #pragma unroll
            for (int wv = 1; wv < 4; ++wv) {
                bl += s_l4[wv];
                bm = fmaxf(bm, s_m4[wv]);
            }
            float* bp = ws + P1_OFF + (size_t)blockIdx.x * 2;
            bp[0] = bm;
            bp[1] = bl;
        }
    }

    grid.sync();

    // ---------------- Phase 2: redundant global reduce (every block) --------
    float M, Ls;
    {
        float m = -1e30f, l = 0.f;
        for (int b = tid; b < NB; b += 256) {
            const float* bp = ws + P1_OFF + (size_t)b * 2;
            l += bp[1];
            m = fmaxf(m, bp[0]);
        }
        sm[tid] = m; sl[tid] = l;
        __syncthreads();
        for (int s = 128; s > 0; s >>= 1) {
            if (tid < s) {
                sl[tid] += sl[tid + s];
                sm[tid] = fmaxf(sm[tid], sm[tid + s]);
            }
            __syncthreads();
        }
        M  = sm[0];                      // bit-identical in every block
        Ls = sl[0] * __expf(-M);         // L_shift = sum(exp(s - M))
        __syncthreads();                 // protect sm reuse in phase 4
    }

    // ---------------- Phase 3: selective P.V + argmax -----------------------
    {
        const float thr = M - 23.0f;
        float acc = 0.f;
        for (int c = wglobal; c < NCHUNKS; c += NWAVES) {
            const float s = ws[SCORES_OFF + (size_t)c * 64 + lane];
            unsigned long long mask = __ballot(s > thr);
            if (mask) {
                if (s == M) ((int*)ws)[HDR_OFF] = c * 64 + lane;
                const float w = __expf(s - M);
                while (mask) {
                    const int b = __ffsll((long long)mask) - 1;
                    mask &= mask - 1;
                    const float wb = __shfl(w, b);
                    acc = fmaf(wb, values[(size_t)(c * 64 + b) * 64 + lane], acc);
                }
            }
        }
        sA[wave][lane] = acc;
        __syncthreads();
        if (tid < 64) {
            ws[PART_OFF + (size_t)blockIdx.x * 64 + tid] =
                (sA[0][tid] + sA[1][tid]) + (sA[2][tid] + sA[3][tid]);
        }
    }

    grid.sync();

    // ---------------- Phase 4: finalize (blocks 0..63) ----------------------
    if (blockIdx.x < 64) {
        const int j = blockIdx.x;
        float v = 0.f;
        for (int b = tid; b < NB; b += 256)
            v += ws[PART_OFF + (size_t)b * 64 + j];
        sm[tid] = v;
        __syncthreads();
        for (int s = 128; s > 0; s >>= 1) {
            if (tid < s) sm[tid] += sm[tid + s];
            __syncthreads();
        }
        if (tid == 0) {
            out[j] = sm[0] / Ls;
            if (j == 0) out[64] = (float)((const int*)ws)[HDR_OFF];
        }
    }
}

extern "C" void kernel_launch(void* const* d_in, const int* in_sizes, int n_in,
                              void* d_out, int out_size, void* d_ws, size_t ws_size,
                              hipStream_t stream) {
    const float* query  = (const float*)d_in[0];
    const float* keys   = (const float*)d_in[1];
    const float* values = (const float*)d_in[2];
    float* out = (float*)d_out;
    float* ws  = (float*)d_ws;

    void* args[] = { (void*)&query, (void*)&keys, (void*)&values,
                     (void*)&ws, (void*)&out };
    hipLaunchCooperativeKernel((void*)nd_fused, dim3(NB), dim3(256),
                               args, 0, stream);
}

// Round 6
// 492.388 us; speedup vs baseline: 1.3791x; 1.3791x over previous
//
#include <hip/hip_runtime.h>
#include <math.h>

#define C_CAP 1000000
#define DIM 64

// ws layout (floats)
#define SCORES_OFF 0          // [1,000,000] raw scores
#define P1_OFF     1000000    // [1024][2] per-block {m, l}
#define ACC_OFF    1002048    // [64] atomic accumulator (zeroed by K_A block 0)
#define HDR_LS     1002112    // L_shift (written by K_B block 0)
#define HDR_ARG    1002113    // argmax (int bits, written by finding thread in K_B)

#define NB1 1024              // K_A grid: 4 blocks/CU, 16 waves/CU
#define NW1 (NB1 * 4)
#define NTILES (C_CAP / 16)   // 62500
#define NB3 2048              // K_B grid
#define NW3 (NB3 * 4)
#define NCHUNKS (C_CAP / 64)  // 15625

// ---------------------------------------------------------------------------
// K_A: stream keys, write raw scores + per-block {max, sum exp(s)} pairs.
// 16-row (4 KB) tiles, double-buffered. Round-5 rocprof showed VGPR_Count=32
// on the fused variant => the compiler sank the prefetch loads to their uses
// (zero MLP, ~630 B in flight/CU). sched_barrier(0) after each LOADK pins the
// prefetch issue before the previous tile's compute to restore the pipeline.
// Block 0 additionally zeroes the ACC region for K_B (cross-dispatch
// visibility is guaranteed at the kernel boundary; no fence needed).
// ---------------------------------------------------------------------------
__global__ __launch_bounds__(256, 4) void nd_scores(
    const float* __restrict__ query,
    const float* __restrict__ keys,
    float* __restrict__ ws)
{
    const int tid  = threadIdx.x;
    const int lane = tid & 63;
    const int wave = tid >> 6;
    const int cl   = lane & 15;
    const int g    = lane >> 4;
    const int wglobal = blockIdx.x * 4 + wave;

    if (blockIdx.x == 0 && tid < 64) ws[ACC_OFF + tid] = 0.f;

    const float4 q4 = ((const float4*)query)[cl];
    const float4* __restrict__ k4p = (const float4*)keys;

    float m = -1e30f, l = 0.f;
    float4 A0, A1, A2, A3;   // current tile
    float4 B0, B1, B2, B3;   // prefetch tile

#define LOADK(b0, b1, b2, b3, tt) {                                        \
        const float4* __restrict__ kp = k4p + (size_t)(tt) * 256 + lane;   \
        b0 = kp[0]; b1 = kp[64]; b2 = kp[128]; b3 = kp[192];               \
        __builtin_amdgcn_sched_barrier(0);                                 \
    }

#define COMPUTE(b0, b1, b2, b3, tt) {                                          \
        float s0 = fmaf(b0.x, q4.x, fmaf(b0.y, q4.y, fmaf(b0.z, q4.z, b0.w * q4.w))); \
        float s1 = fmaf(b1.x, q4.x, fmaf(b1.y, q4.y, fmaf(b1.z, q4.z, b1.w * q4.w))); \
        float s2 = fmaf(b2.x, q4.x, fmaf(b2.y, q4.y, fmaf(b2.z, q4.z, b2.w * q4.w))); \
        float s3 = fmaf(b3.x, q4.x, fmaf(b3.y, q4.y, fmaf(b3.z, q4.z, b3.w * q4.w))); \
        s0 += __shfl_xor(s0, 1); s1 += __shfl_xor(s1, 1);                      \
        s2 += __shfl_xor(s2, 1); s3 += __shfl_xor(s3, 1);                      \
        s0 += __shfl_xor(s0, 2); s1 += __shfl_xor(s1, 2);                      \
        s2 += __shfl_xor(s2, 2); s3 += __shfl_xor(s3, 2);                      \
        s0 += __shfl_xor(s0, 4); s1 += __shfl_xor(s1, 4);                      \
        s2 += __shfl_xor(s2, 4); s3 += __shfl_xor(s3, 4);                      \
        s0 += __shfl_xor(s0, 8); s1 += __shfl_xor(s1, 8);                      \
        s2 += __shfl_xor(s2, 8); s3 += __shfl_xor(s3, 8);                      \
        const float sv = (cl == 0) ? s0 : (cl == 1) ? s1 : (cl == 2) ? s2 : s3; \
        if (cl < 4) ws[SCORES_OFF + (tt) * 16 + 4 * cl + g] = sv;              \
        l += (__expf(s0) + __expf(s1)) + (__expf(s2) + __expf(s3));            \
        m = fmaxf(m, fmaxf(fmaxf(s0, s1), fmaxf(s2, s3)));                     \
    }

    int t = wglobal;                 // wglobal < 4096 <= NTILES: always valid
    LOADK(A0, A1, A2, A3, t);
    while (true) {
        const int tn = t + NW1;
        if (tn < NTILES) LOADK(B0, B1, B2, B3, tn);
        COMPUTE(A0, A1, A2, A3, t);
        if (tn >= NTILES) break;
        t = tn + NW1;
        if (t < NTILES) LOADK(A0, A1, A2, A3, t);
        COMPUTE(B0, B1, B2, B3, tn);
        if (t >= NTILES) break;
    }
#undef LOADK
#undef COMPUTE

    // combine the 4 16-lane groups inside the wave
    l += __shfl_xor(l, 16); m = fmaxf(m, __shfl_xor(m, 16));
    l += __shfl_xor(l, 32); m = fmaxf(m, __shfl_xor(m, 32));

    __shared__ float s_m[4], s_l[4];
    if (lane == 0) { s_m[wave] = m; s_l[wave] = l; }
    __syncthreads();
    if (tid == 0) {
        float bm = s_m[0], bl = s_l[0];
        #pragma unroll
        for (int wv = 1; wv < 4; ++wv) {
            bl += s_l[wv];
            bm = fmaxf(bm, s_m[wv]);
        }
        float* bp = ws + P1_OFF + (size_t)blockIdx.x * 2;
        bp[0] = bm;
        bp[1] = bl;
    }
}

// ---------------------------------------------------------------------------
// K_B: redundant M/L reduce (every block reduces the 1024 {m,l} pairs — 8 KB,
// L2-resident, bit-identical result in all blocks; replaces the old K2
// dispatch) then selective P.V + argmax capture. Rows with s > M-23
// (exp(s-M) > 1e-10, ~1e4 of 1e6) trigger a wave-coalesced 256 B value-row
// load + fma. argmax via exact-bit equality s == M (M is an fmax chain over
// exactly the stored score bits). Block 0 publishes L_shift for K_C.
// ---------------------------------------------------------------------------
__global__ __launch_bounds__(256, 8) void nd_pv(
    const float* __restrict__ values,
    float* __restrict__ ws)
{
    const int tid  = threadIdx.x;
    const int lane = tid & 63;
    const int wave = tid >> 6;
    const int wglobal = blockIdx.x * 4 + wave;

    // --- redundant global {M, L} reduce (identical in every block) ---
    float m = -1e30f, l = 0.f;
    for (int b = tid; b < NB1; b += 256) {
        const float* bp = ws + P1_OFF + (size_t)b * 2;
        l += bp[1];
        m = fmaxf(m, bp[0]);
    }
    __shared__ float sm[256], sl[256];
    sm[tid] = m; sl[tid] = l;
    __syncthreads();
    for (int s = 128; s > 0; s >>= 1) {
        if (tid < s) {
            sl[tid] += sl[tid + s];
            sm[tid] = fmaxf(sm[tid], sm[tid + s]);
        }
        __syncthreads();
    }
    const float M  = sm[0];
    const float Ls = sl[0] * __expf(-M);
    if (blockIdx.x == 0 && tid == 0) ws[HDR_LS] = Ls;

    // --- selective P.V + argmax ---
    const float thr = M - 23.0f;
    float acc = 0.f;
    for (int c = wglobal; c < NCHUNKS; c += NW3) {
        const float s = ws[SCORES_OFF + (size_t)c * 64 + lane];
        unsigned long long mask = __ballot(s > thr);
        if (mask) {
            if (s == M) ((int*)ws)[HDR_ARG] = c * 64 + lane;
            const float w = __expf(s - M);
            while (mask) {
                const int b = __ffsll((long long)mask) - 1;
                mask &= mask - 1;
                const float wb = __shfl(w, b);
                acc = fmaf(wb, values[(size_t)(c * 64 + b) * 64 + lane], acc);
            }
        }
    }

    __shared__ float sA[4][64];
    sA[wave][lane] = acc;
    __syncthreads();
    if (tid < 64) {
        const float v = (sA[0][tid] + sA[1][tid]) + (sA[2][tid] + sA[3][tid]);
        if (v != 0.f) atomicAdd(ws + ACC_OFF + tid, v);
    }
}

// ---------------------------------------------------------------------------
// K_C: finalize. out[0..63] = acc / L_shift; out[64] = argmax as float.
// ---------------------------------------------------------------------------
__global__ __launch_bounds__(128) void nd_final(
    const float* __restrict__ ws, float* __restrict__ out)
{
    const int tid = threadIdx.x;
    if (tid < 64) out[tid] = ws[ACC_OFF + tid] / ws[HDR_LS];
    if (tid == 64) out[64] = (float)((const int*)ws)[HDR_ARG];
}

extern "C" void kernel_launch(void* const* d_in, const int* in_sizes, int n_in,
                              void* d_out, int out_size, void* d_ws, size_t ws_size,
                              hipStream_t stream) {
    const float* query  = (const float*)d_in[0];
    const float* keys   = (const float*)d_in[1];
    const float* values = (const float*)d_in[2];
    float* out = (float*)d_out;
    float* ws  = (float*)d_ws;

    nd_scores<<<NB1, 256, 0, stream>>>(query, keys, ws);
    nd_pv<<<NB3, 256, 0, stream>>>(values, ws);
    nd_final<<<1, 128, 0, stream>>>(ws, out);
}

// Round 7
// 491.677 us; speedup vs baseline: 1.3811x; 1.0014x over previous
//
#include <hip/hip_runtime.h>
#include <math.h>

#define C_CAP 1000000
#define DIM 64

// ws layout (floats)
#define SCORES_OFF 0          // [1,000,000] raw scores
#define P1_OFF     1000000    // [2048][2] per-block {m, l}
#define ACC_OFF    1004096    // [64] atomic accumulator (zeroed by K_A block 0)
#define HDR_LS     1004160    // L_shift (written by K_B block 0)
#define HDR_ARG    1004161    // argmax (int bits, written by finding thread in K_B)

#define NB1 2048              // K_A grid: 8 blocks/CU, 32 waves/CU (copy-ubench regime)
#define NW1 (NB1 * 4)         // 8192 waves
#define NTILES (C_CAP / 16)   // 62500
#define NB3 2048              // K_B grid
#define NW3 (NB3 * 4)
#define NCHUNKS (C_CAP / 64)  // 15625

// ---------------------------------------------------------------------------
// K_A: stream keys, write raw scores + per-block {max, sum exp(s)} pairs.
//
// BW model from R5/R6 counters: streaming-read BW ~ (waves/CU) x (bytes in
// flight per wave). The R5 fused profile (VGPR_Count=32) proved the compiler
// collapses a named-register double-buffer and sinks loads to uses (~1-4 KB
// in flight/wave); at 16 waves/CU that pencils to the observed ~2.5 TB/s.
// The m13 copy ubench reaches 6.3 TB/s at 32 waves/CU with ~1 KB/wave.
// => This round: 32 waves/CU (NB1=2048, launch_bounds(256,8)), lean VGPR
// (no manual double-buffer -- it collapsed anyway and would break the
// 64-VGPR/8-waves-per-EU budget). sched_barrier(0) reverted (R6: harmful,
// consistent with learn_hip m141).
//
// Lane layout per 16-row (4 KB) tile: load j covers rows 16t+4j+g (g=lane>>4),
// cl=lane&15 owns cols 4cl..4cl+3. Scores are one contiguous 64 B segment per
// tile. l accumulates UNSHIFTED sum(exp(s)) (max score ~42 -> <=1e20, fp32-safe).
// argmax is NOT tracked here: K_B recovers it via exact-bit equality with M.
// Block 0 zeroes ACC for K_B (cross-dispatch visibility at kernel boundary).
// ---------------------------------------------------------------------------
__global__ __launch_bounds__(256, 8) void nd_scores(
    const float* __restrict__ query,
    const float* __restrict__ keys,
    float* __restrict__ ws)
{
    const int tid  = threadIdx.x;
    const int lane = tid & 63;
    const int wave = tid >> 6;
    const int cl   = lane & 15;
    const int g    = lane >> 4;
    const int wglobal = blockIdx.x * 4 + wave;

    if (blockIdx.x == 0 && tid < 64) ws[ACC_OFF + tid] = 0.f;

    const float4 q4 = ((const float4*)query)[cl];
    const float4* __restrict__ k4p = (const float4*)keys;

    float m = -1e30f, l = 0.f;

    for (int t = wglobal; t < NTILES; t += NW1) {
        const float4* __restrict__ kp = k4p + (size_t)t * 256 + lane;
        float4 k0 = kp[0];
        float4 k1 = kp[64];
        float4 k2 = kp[128];
        float4 k3 = kp[192];

        float s0 = fmaf(k0.x, q4.x, fmaf(k0.y, q4.y, fmaf(k0.z, q4.z, k0.w * q4.w)));
        float s1 = fmaf(k1.x, q4.x, fmaf(k1.y, q4.y, fmaf(k1.z, q4.z, k1.w * q4.w)));
        float s2 = fmaf(k2.x, q4.x, fmaf(k2.y, q4.y, fmaf(k2.z, q4.z, k2.w * q4.w)));
        float s3 = fmaf(k3.x, q4.x, fmaf(k3.y, q4.y, fmaf(k3.z, q4.z, k3.w * q4.w)));

        // 4 independent 4-deep cross-lane dot reductions, interleaved
        s0 += __shfl_xor(s0, 1); s1 += __shfl_xor(s1, 1);
        s2 += __shfl_xor(s2, 1); s3 += __shfl_xor(s3, 1);
        s0 += __shfl_xor(s0, 2); s1 += __shfl_xor(s1, 2);
        s2 += __shfl_xor(s2, 2); s3 += __shfl_xor(s3, 2);
        s0 += __shfl_xor(s0, 4); s1 += __shfl_xor(s1, 4);
        s2 += __shfl_xor(s2, 4); s3 += __shfl_xor(s3, 4);
        s0 += __shfl_xor(s0, 8); s1 += __shfl_xor(s1, 8);
        s2 += __shfl_xor(s2, 8); s3 += __shfl_xor(s3, 8);

        // write the 16 scores: lane (g, cl=j) writes row 16t + 4j + g
        const float sv = (cl == 0) ? s0 : (cl == 1) ? s1 : (cl == 2) ? s2 : s3;
        if (cl < 4) ws[SCORES_OFF + t * 16 + 4 * cl + g] = sv;

        l += (__expf(s0) + __expf(s1)) + (__expf(s2) + __expf(s3));
        m = fmaxf(m, fmaxf(fmaxf(s0, s1), fmaxf(s2, s3)));
    }

    // combine the 4 16-lane groups inside the wave
    l += __shfl_xor(l, 16); m = fmaxf(m, __shfl_xor(m, 16));
    l += __shfl_xor(l, 32); m = fmaxf(m, __shfl_xor(m, 32));

    __shared__ float s_m[4], s_l[4];
    if (lane == 0) { s_m[wave] = m; s_l[wave] = l; }
    __syncthreads();
    if (tid == 0) {
        float bm = s_m[0], bl = s_l[0];
        #pragma unroll
        for (int wv = 1; wv < 4; ++wv) {
            bl += s_l[wv];
            bm = fmaxf(bm, s_m[wv]);
        }
        float* bp = ws + P1_OFF + (size_t)blockIdx.x * 2;
        bp[0] = bm;
        bp[1] = bl;
    }
}

// ---------------------------------------------------------------------------
// K_B: redundant M/L reduce (every block reduces the 2048 {m,l} pairs — 16 KB,
// L2-resident, bit-identical result in all blocks) then selective P.V +
// argmax capture. Rows with s > M-23 (exp(s-M) > 1e-10, ~1e4 of 1e6) trigger
// a wave-coalesced 256 B value-row load + fma; exp computed only for active
// chunks (~1%). argmax via exact-bit equality s == M (M is an fmax chain over
// exactly the stored score bits). Block 0 publishes L_shift for K_C.
// ---------------------------------------------------------------------------
__global__ __launch_bounds__(256, 8) void nd_pv(
    const float* __restrict__ values,
    float* __restrict__ ws)
{
    const int tid  = threadIdx.x;
    const int lane = tid & 63;
    const int wave = tid >> 6;
    const int wglobal = blockIdx.x * 4 + wave;

    // --- redundant global {M, L} reduce (identical in every block) ---
    float m = -1e30f, l = 0.f;
    for (int b = tid; b < NB1; b += 256) {
        const float* bp = ws + P1_OFF + (size_t)b * 2;
        l += bp[1];
        m = fmaxf(m, bp[0]);
    }
    __shared__ float sm[256], sl[256];
    sm[tid] = m; sl[tid] = l;
    __syncthreads();
    for (int s = 128; s > 0; s >>= 1) {
        if (tid < s) {
            sl[tid] += sl[tid + s];
            sm[tid] = fmaxf(sm[tid], sm[tid + s]);
        }
        __syncthreads();
    }
    const float M  = sm[0];
    const float Ls = sl[0] * __expf(-M);
    if (blockIdx.x == 0 && tid == 0) ws[HDR_LS] = Ls;

    // --- selective P.V + argmax ---
    const float thr = M - 23.0f;
    float acc = 0.f;
    for (int c = wglobal; c < NCHUNKS; c += NW3) {
        const float s = ws[SCORES_OFF + (size_t)c * 64 + lane];
        unsigned long long mask = __ballot(s > thr);
        if (mask) {
            if (s == M) ((int*)ws)[HDR_ARG] = c * 64 + lane;
            const float w = __expf(s - M);
            while (mask) {
                const int b = __ffsll((long long)mask) - 1;
                mask &= mask - 1;
                const float wb = __shfl(w, b);
                acc = fmaf(wb, values[(size_t)(c * 64 + b) * 64 + lane], acc);
            }
        }
    }

    __shared__ float sA[4][64];
    sA[wave][lane] = acc;
    __syncthreads();
    if (tid < 64) {
        const float v = (sA[0][tid] + sA[1][tid]) + (sA[2][tid] + sA[3][tid]);
        if (v != 0.f) atomicAdd(ws + ACC_OFF + tid, v);
    }
}

// ---------------------------------------------------------------------------
// K_C: finalize. out[0..63] = acc / L_shift; out[64] = argmax as float.
// ---------------------------------------------------------------------------
__global__ __launch_bounds__(128) void nd_final(
    const float* __restrict__ ws, float* __restrict__ out)
{
    const int tid = threadIdx.x;
    if (tid < 64) out[tid] = ws[ACC_OFF + tid] / ws[HDR_LS];
    if (tid == 64) out[64] = (float)((const int*)ws)[HDR_ARG];
}

extern "C" void kernel_launch(void* const* d_in, const int* in_sizes, int n_in,
                              void* d_out, int out_size, void* d_ws, size_t ws_size,
                              hipStream_t stream) {
    const float* query  = (const float*)d_in[0];
    const float* keys   = (const float*)d_in[1];
    const float* values = (const float*)d_in[2];
    float* out = (float*)d_out;
    float* ws  = (float*)d_ws;

    nd_scores<<<NB1, 256, 0, stream>>>(query, keys, ws);
    nd_pv<<<NB3, 256, 0, stream>>>(values, ws);
    nd_final<<<1, 128, 0, stream>>>(ws, out);
}